// Round 12
// baseline (363.750 us; speedup 1.0000x reference)
//
#include <hip/hip_runtime.h>
#include <hip/hip_bf16.h>

#define M_DIM 4096
#define K_DIM 4096
#define N_DIM 16384
#define BM 256
#define BN 256
#define BKB 128                    // K-bytes (=int8 elems) per LDS tile row
#define NT (K_DIM / BKB)           // 32 K-tiles
#define HALF_B 16384               // bytes per half-tile (128 rows x 128 B)
#define BUF_B  (4 * HALF_B)        // 4 half-slots per buffer: A0,A1,B0,B1
#define LDS_BYTES (2 * BUF_B)      // 131072 B

#define QX_BLOCKS M_DIM                              // 4096 quant blocks
#define CW_BLOCKS ((N_DIM * K_DIM) / (256 * 16))     // 16384 weight blocks

using i32x4 = __attribute__((ext_vector_type(4))) int;

// ---------- fused prep: blocks [0,4096) quantize x rows; rest pack weights --
// Both parts are memory-bound with disjoint traffic; one launch lets them
// run concurrently instead of serialized (saves a launch + overlaps tails).
__global__ __launch_bounds__(256) void prep_kernel(
    const float* __restrict__ x, const int* __restrict__ w,
    signed char* __restrict__ q, float* __restrict__ xs,
    signed char* __restrict__ wq) {
    int bid = blockIdx.x;
    int tid = threadIdx.x;

    if (bid < QX_BLOCKS) {
        // ---- per-row symmetric int8 quant of x, scale = rowmax/127 ----
        int row = bid;
        const float* xr = x + (size_t)row * K_DIM + tid * 16;
        float4 v0 = *reinterpret_cast<const float4*>(xr + 0);
        float4 v1 = *reinterpret_cast<const float4*>(xr + 4);
        float4 v2 = *reinterpret_cast<const float4*>(xr + 8);
        float4 v3 = *reinterpret_cast<const float4*>(xr + 12);
        float f[16] = {v0.x, v0.y, v0.z, v0.w, v1.x, v1.y, v1.z, v1.w,
                       v2.x, v2.y, v2.z, v2.w, v3.x, v3.y, v3.z, v3.w};
        float m = 0.f;
        #pragma unroll
        for (int i = 0; i < 16; ++i) m = fmaxf(m, fabsf(f[i]));
        #pragma unroll
        for (int off = 32; off > 0; off >>= 1) m = fmaxf(m, __shfl_xor(m, off));
        __shared__ float red[4];
        if ((tid & 63) == 0) red[tid >> 6] = m;
        __syncthreads();
        m = fmaxf(fmaxf(red[0], red[1]), fmaxf(red[2], red[3]));
        float inv = (m > 0.f) ? 127.0f / m : 0.f;
        if (tid == 0) xs[row] = (m > 0.f) ? m / 127.0f : 0.f;
        int b[16];
        #pragma unroll
        for (int i = 0; i < 16; ++i) {
            float t = f[i] * inv;
            t = fminf(fmaxf(t, -127.f), 127.f);
            b[i] = (int)__builtin_rintf(t);
        }
        int4 p;
        p.x = (b[0] & 255) | ((b[1] & 255) << 8) | ((b[2] & 255) << 16) | (b[3] << 24);
        p.y = (b[4] & 255) | ((b[5] & 255) << 8) | ((b[6] & 255) << 16) | (b[7] << 24);
        p.z = (b[8] & 255) | ((b[9] & 255) << 8) | ((b[10] & 255) << 16) | (b[11] << 24);
        p.w = (b[12] & 255) | ((b[13] & 255) << 8) | ((b[14] & 255) << 16) | (b[15] << 24);
        *reinterpret_cast<int4*>(q + (size_t)row * K_DIM + tid * 16) = p;
    } else {
        // ---- weight pack: int32 (harness int8-as-int) -> packed int8 ----
        int base = ((bid - QX_BLOCKS) * 256 + tid) * 16;
        int4 a = *reinterpret_cast<const int4*>(w + base);
        int4 b = *reinterpret_cast<const int4*>(w + base + 4);
        int4 c = *reinterpret_cast<const int4*>(w + base + 8);
        int4 d = *reinterpret_cast<const int4*>(w + base + 12);
        int4 p;
        p.x = (a.x & 255) | ((a.y & 255) << 8) | ((a.z & 255) << 16) | (a.w << 24);
        p.y = (b.x & 255) | ((b.y & 255) << 8) | ((b.z & 255) << 16) | (b.w << 24);
        p.z = (c.x & 255) | ((c.y & 255) << 8) | ((c.z & 255) << 16) | (c.w << 24);
        p.w = (d.x & 255) | ((d.y & 255) << 8) | ((d.z & 255) << 16) | (d.w << 24);
        *reinterpret_cast<int4*>(wq + base) = p;
    }
}

#define FENCE() asm volatile("" ::: "memory")
#define BARRIER() do { FENCE(); __builtin_amdgcn_s_barrier(); FENCE(); } while (0)

// Read A-half AH's fragments into af (8 x ds_read_b128).
#define READ_A(AH)                                                        \
  do { _Pragma("unroll") for (int mi = 0; mi < 4; ++mi) {                 \
    int hr = wm * 64 + mi * 16 + l15;                                     \
    const signed char* hb = lb + (AH) * HALF_B + hr * BKB;                \
    _Pragma("unroll") for (int kk = 0; kk < 2; ++kk)                      \
      af[mi][kk] = *reinterpret_cast<const i32x4*>(                       \
          hb + (((kk * 4 + lg) ^ (hr & 7)) * 16));                        \
  } } while (0)

// Read B-group BG's fragments into DST (4 x ds_read_b128).
#define READ_B(DST, BG)                                                   \
  do { _Pragma("unroll") for (int ni = 0; ni < 2; ++ni) {                 \
    int hr = wn * 32 + ni * 16 + l15;                                     \
    const signed char* hb = lb + (2 + (BG)) * HALF_B + hr * BKB;          \
    _Pragma("unroll") for (int kk = 0; kk < 2; ++kk)                      \
      DST[ni][kk] = *reinterpret_cast<const i32x4*>(                      \
          hb + (((kk * 4 + lg) ^ (hr & 7)) * 16));                        \
  } } while (0)

// 16-MFMA quadrant cluster (i8 K=64), setprio'd (T5).  Static acc idx.
#define MFMA16(BSRC, AH, BG)                                              \
  do { __builtin_amdgcn_s_setprio(1);                                     \
    _Pragma("unroll") for (int kk = 0; kk < 2; ++kk)                      \
      _Pragma("unroll") for (int mi = 0; mi < 4; ++mi)                    \
        _Pragma("unroll") for (int ni = 0; ni < 2; ++ni)                  \
          acc[AH][BG][mi][ni] = __builtin_amdgcn_mfma_i32_16x16x64_i8(    \
              af[mi][kk], BSRC[ni][kk], acc[AH][BG][mi][ni], 0, 0, 0);    \
    __builtin_amdgcn_s_setprio(0);                                        \
  } while (0)

// C[m][o] = xs[m] * scale[o] * (int dot of Xq[m,:], Wq[o,:]) + bias[o]
// Xq:[M][K] i8, Wq:[N][K] i8 (B^T layout), C:[M][N] f32.
// Round-6 proven schedule: 256x256 tile, 4 quadrant-phases/K-tile (Gray
// order A0B0,A0B1,A1B1,A1B0), B0/B1 register-resident, 2 barriers/K-tile,
// counted vmcnt(4) immediately before the tile barrier (never 0 mid-loop).
__global__ __launch_bounds__(512, 2) void gemm_kernel(
    const signed char* __restrict__ A,
    const signed char* __restrict__ B,
    const float* __restrict__ scale,
    const float* __restrict__ xs,
    const float* __restrict__ bias,
    float* __restrict__ C)
{
    extern __shared__ signed char lds[];   // 2 x 64KB

    // bijective XCD swizzle: nwg = 16*64 = 1024, divisible by 8
    const int nwg = (M_DIM / BM) * (N_DIM / BN);
    const int cpx = nwg / 8;
    int bid = blockIdx.x;
    int swz = (bid & 7) * cpx + (bid >> 3);
    const int ntn = N_DIM / BN;               // 64
    int tm = swz / ntn;
    int tn = swz % ntn;

    int tid  = threadIdx.x;
    int lane = tid & 63;
    int wid  = tid >> 6;      // 8 waves: 2 (M) x 4 (N)
    int wm   = wid >> 2;      // 0..1
    int wn   = wid & 3;       // 0..3
    int l15  = lane & 15;
    int lg   = lane >> 4;

    const signed char* Ab = A + (size_t)tm * BM * K_DIM;
    const signed char* Bb = B + (size_t)tn * BN * K_DIM;

    // Stage one half-tile (128 rows x 128 B = 16KB) into buffer `buf`, slot
    // `half` (0=A0,1=A1,2=B0,3=B1), K-tile t.  2 gload_lds per thread.
    // Chunk swizzle ch^(row&7) on the GLOBAL source (rule #21); LDS dest
    // linear.
    auto STAGE = [&](int buf, int half, int t) {
        const signed char* gbase = (half < 2)
            ? Ab + (size_t)(half * 128) * K_DIM
            : Bb + (size_t)((half - 2) * 128) * K_DIM;
        signed char* dbase = lds + buf * BUF_B + half * HALF_B;
        #pragma unroll
        for (int i = 0; i < 2; ++i) {
            int flat = i * 512 + tid;            // 16B-chunk id 0..1023
            int row = flat >> 3, ch = flat & 7;
            const signed char* src =
                gbase + (size_t)row * K_DIM + t * BKB + ((ch ^ (row & 7)) * 16);
            __builtin_amdgcn_global_load_lds(
                (const __attribute__((address_space(1))) unsigned int*)src,
                (__attribute__((address_space(3))) unsigned int*)(dbase + flat * 16),
                16, 0, 0);
        }
    };

    i32x4 acc[2][2][4][2];
    #pragma unroll
    for (int a0 = 0; a0 < 2; ++a0)
      #pragma unroll
      for (int g0 = 0; g0 < 2; ++g0)
        #pragma unroll
        for (int mi = 0; mi < 4; ++mi)
          #pragma unroll
          for (int ni = 0; ni < 2; ++ni)
            acc[a0][g0][mi][ni] = (i32x4){0, 0, 0, 0};

    i32x4 af[4][2], b0[2][2], b1[2][2];

    // Prologue: tile0 complete + A0(1),B1(1) in flight (steady state).
    STAGE(0, 0, 0);   // A0(0)
    STAGE(0, 2, 0);   // B0(0)
    STAGE(0, 3, 0);   // B1(0)
    STAGE(0, 1, 0);   // A1(0)
    STAGE(1, 0, 1);   // A0(1)
    STAGE(1, 3, 1);   // B1(1)
    asm volatile("s_waitcnt vmcnt(4)" ::: "memory");  // tile0's 8 loads landed

    for (int t = 0; t < NT; ++t) {
        const signed char* lb = lds + (t & 1) * BUF_B;
        const bool s1 = (t + 1) < NT;
        const bool s2 = (t + 2) < NT;

        BARRIER();                              // tile-boundary barrier
        if (s1) STAGE((t + 1) & 1, 1, t + 1);   // A1(t+1): slot retired P3(t-1)
        READ_A(0);
        READ_B(b0, 0);
        MFMA16(b0, 0, 0);                       // P1: A0 x B0
        if (s1) STAGE((t + 1) & 1, 2, t + 1);   // B0(t+1): slot retired P1(t-1)
        READ_B(b1, 1);
        MFMA16(b1, 0, 1);                       // P2: A0 x B1
        BARRIER();                              // mid-tile barrier
        if (s2) STAGE(t & 1, 0, t + 2);         // A0(t+2): A0(t) reads done P1
        READ_A(1);
        MFMA16(b1, 1, 1);                       // P3: A1 x B1
        if (s2) STAGE(t & 1, 3, t + 2);         // B1(t+2): B1(t) reads done P2
        MFMA16(b0, 1, 0);                       // P4: A1 x B0 (no reads)
        // Boundary wait BEFORE next tile's barrier.  Leaves 2 stages in flight.
        if (s2) asm volatile("s_waitcnt vmcnt(4)" ::: "memory");
        else    asm volatile("s_waitcnt vmcnt(0)" ::: "memory");
    }

    // Epilogue: 16x16 C/D layout col = lane&15, row = (lane>>4)*4 + reg (m89;
    // dtype-independent incl. i8 per m121-128).
    #pragma unroll
    for (int AH = 0; AH < 2; ++AH)
      #pragma unroll
      for (int BG = 0; BG < 2; ++BG)
        #pragma unroll
        for (int ni = 0; ni < 2; ++ni) {
            int col = tn * BN + BG * 128 + wn * 32 + ni * 16 + l15;
            float s = scale[col];
            float b = bias[col];
            #pragma unroll
            for (int mi = 0; mi < 4; ++mi) {
                int row0 = tm * BM + AH * 128 + wm * 64 + mi * 16 + lg * 4;
                float4 x4 = *reinterpret_cast<const float4*>(xs + row0);
                float xv[4] = {x4.x, x4.y, x4.z, x4.w};
                #pragma unroll
                for (int r = 0; r < 4; ++r)
                    C[(size_t)(row0 + r) * N_DIM + col] =
                        (float)acc[AH][BG][mi][ni][r] * (s * xv[r]) + b;
            }
        }
}

// safety net if workspace is too small
__global__ void naive_kernel(const float* __restrict__ x,
                             const int* __restrict__ w,
                             const float* __restrict__ scale,
                             const float* __restrict__ bias,
                             float* __restrict__ out) {
    long long idx = (long long)blockIdx.x * blockDim.x + threadIdx.x;
    long long total = (long long)M_DIM * N_DIM;
    if (idx >= total) return;
    int m = (int)(idx / N_DIM);
    int o = (int)(idx % N_DIM);
    const float* xr = x + (size_t)m * K_DIM;
    const int* wr = w + (size_t)o * K_DIM;
    float sum = 0.f;
    for (int k = 0; k < K_DIM; ++k) sum += xr[k] * (float)wr[k];
    out[idx] = sum * scale[o] + bias[o];
}

extern "C" void kernel_launch(void* const* d_in, const int* in_sizes, int n_in,
                              void* d_out, int out_size, void* d_ws, size_t ws_size,
                              hipStream_t stream)
{
    const float* x     = (const float*)d_in[0];
    const int*   w     = (const int*)d_in[1];
    const float* scale = (const float*)d_in[2];
    const float* bias  = (const float*)d_in[3];
    float*       out   = (float*)d_out;

    const size_t needW = (size_t)N_DIM * K_DIM;            // 64MB int8
    const size_t needX = (size_t)M_DIM * K_DIM;            // 16MB int8
    const size_t needS = (size_t)M_DIM * sizeof(float);    // 16KB

    if (ws_size >= needW + needX + needS) {
        signed char* Wq = (signed char*)d_ws;
        signed char* Xq = (signed char*)((char*)d_ws + needW);
        float*       xs = (float*)((char*)d_ws + needW + needX);
        hipLaunchKernelGGL(prep_kernel, dim3(QX_BLOCKS + CW_BLOCKS), dim3(256),
                           0, stream, x, w, Xq, xs, Wq);
        hipLaunchKernelGGL(gemm_kernel, dim3((M_DIM / BM) * (N_DIM / BN)), dim3(512),
                           LDS_BYTES, stream, Xq, Wq, scale, xs, bias, out);
    } else {
        long long total = (long long)M_DIM * N_DIM;
        int blocks = (int)((total + 255) / 256);
        hipLaunchKernelGGL(naive_kernel, dim3(blocks), dim3(256), 0, stream,
                           x, w, scale, bias, out);
    }
}

// Round 13
// 348.462 us; speedup vs baseline: 1.0439x; 1.0439x over previous
//
#include <hip/hip_runtime.h>
#include <hip/hip_bf16.h>

#define M_DIM 4096
#define K_DIM 4096
#define N_DIM 16384
#define BM 256
#define BN 256
#define BKB 128                    // K-bytes (=int8 elems) per LDS tile row
#define NT (K_DIM / BKB)           // 32 K-tiles
#define HALF_B 16384               // bytes per half-tile (128 rows x 128 B)
#define BUF_B  (4 * HALF_B)        // 4 half-slots per buffer: A0,A1,B0,B1
#define LDS_BYTES (2 * BUF_B)      // 131072 B

using i32x4 = __attribute__((ext_vector_type(4))) int;

// ---------- weight conversion: int32 (harness) -> packed int8 ----------
__global__ void cvt_w_kernel(const int* __restrict__ w,
                             signed char* __restrict__ o, int n) {
    int tid = blockIdx.x * blockDim.x + threadIdx.x;
    int stride = gridDim.x * blockDim.x;
    for (int base = tid * 16; base < n; base += stride * 16) {
        int4 a = *reinterpret_cast<const int4*>(w + base);
        int4 b = *reinterpret_cast<const int4*>(w + base + 4);
        int4 c = *reinterpret_cast<const int4*>(w + base + 8);
        int4 d = *reinterpret_cast<const int4*>(w + base + 12);
        int4 p;
        p.x = (a.x & 255) | ((a.y & 255) << 8) | ((a.z & 255) << 16) | (a.w << 24);
        p.y = (b.x & 255) | ((b.y & 255) << 8) | ((b.z & 255) << 16) | (b.w << 24);
        p.z = (c.x & 255) | ((c.y & 255) << 8) | ((c.z & 255) << 16) | (c.w << 24);
        p.w = (d.x & 255) | ((d.y & 255) << 8) | ((d.z & 255) << 16) | (d.w << 24);
        *reinterpret_cast<int4*>(o + base) = p;
    }
}

// ---------- x quantization: per-row symmetric int8, scale = rowmax/127 ----
__global__ __launch_bounds__(256) void quant_x_kernel(
    const float* __restrict__ x, signed char* __restrict__ q,
    float* __restrict__ xs) {
    int row = blockIdx.x;
    int tid = threadIdx.x;
    const float* xr = x + (size_t)row * K_DIM + tid * 16;
    float4 v0 = *reinterpret_cast<const float4*>(xr + 0);
    float4 v1 = *reinterpret_cast<const float4*>(xr + 4);
    float4 v2 = *reinterpret_cast<const float4*>(xr + 8);
    float4 v3 = *reinterpret_cast<const float4*>(xr + 12);
    float f[16] = {v0.x, v0.y, v0.z, v0.w, v1.x, v1.y, v1.z, v1.w,
                   v2.x, v2.y, v2.z, v2.w, v3.x, v3.y, v3.z, v3.w};
    float m = 0.f;
    #pragma unroll
    for (int i = 0; i < 16; ++i) m = fmaxf(m, fabsf(f[i]));
    #pragma unroll
    for (int off = 32; off > 0; off >>= 1) m = fmaxf(m, __shfl_xor(m, off));
    __shared__ float red[4];
    if ((tid & 63) == 0) red[tid >> 6] = m;
    __syncthreads();
    m = fmaxf(fmaxf(red[0], red[1]), fmaxf(red[2], red[3]));
    float inv = (m > 0.f) ? 127.0f / m : 0.f;
    if (tid == 0) xs[row] = (m > 0.f) ? m / 127.0f : 0.f;
    int b[16];
    #pragma unroll
    for (int i = 0; i < 16; ++i) {
        float t = f[i] * inv;
        t = fminf(fmaxf(t, -127.f), 127.f);
        b[i] = (int)__builtin_rintf(t);
    }
    int4 p;
    p.x = (b[0] & 255) | ((b[1] & 255) << 8) | ((b[2] & 255) << 16) | (b[3] << 24);
    p.y = (b[4] & 255) | ((b[5] & 255) << 8) | ((b[6] & 255) << 16) | (b[7] << 24);
    p.z = (b[8] & 255) | ((b[9] & 255) << 8) | ((b[10] & 255) << 16) | (b[11] << 24);
    p.w = (b[12] & 255) | ((b[13] & 255) << 8) | ((b[14] & 255) << 16) | (b[15] << 24);
    *reinterpret_cast<int4*>(q + (size_t)row * K_DIM + tid * 16) = p;
}

#define FENCE() asm volatile("" ::: "memory")
#define BARRIER() do { FENCE(); __builtin_amdgcn_s_barrier(); FENCE(); } while (0)

// Read A-half AH's fragments into af (8 x ds_read_b128).
#define READ_A(AH)                                                        \
  do { _Pragma("unroll") for (int mi = 0; mi < 4; ++mi) {                 \
    int hr = wm * 64 + mi * 16 + l15;                                     \
    const signed char* hb = lb + (AH) * HALF_B + hr * BKB;                \
    _Pragma("unroll") for (int kk = 0; kk < 2; ++kk)                      \
      af[mi][kk] = *reinterpret_cast<const i32x4*>(                       \
          hb + (((kk * 4 + lg) ^ (hr & 7)) * 16));                        \
  } } while (0)

// Read B-group BG's fragments into DST (4 x ds_read_b128).
#define READ_B(DST, BG)                                                   \
  do { _Pragma("unroll") for (int ni = 0; ni < 2; ++ni) {                 \
    int hr = wn * 32 + ni * 16 + l15;                                     \
    const signed char* hb = lb + (2 + (BG)) * HALF_B + hr * BKB;          \
    _Pragma("unroll") for (int kk = 0; kk < 2; ++kk)                      \
      DST[ni][kk] = *reinterpret_cast<const i32x4*>(                      \
          hb + (((kk * 4 + lg) ^ (hr & 7)) * 16));                        \
  } } while (0)

// 16-MFMA quadrant cluster (i8 K=64), setprio'd (T5).  Static acc idx.
#define MFMA16(BSRC, AH, BG)                                              \
  do { __builtin_amdgcn_s_setprio(1);                                     \
    _Pragma("unroll") for (int kk = 0; kk < 2; ++kk)                      \
      _Pragma("unroll") for (int mi = 0; mi < 4; ++mi)                    \
        _Pragma("unroll") for (int ni = 0; ni < 2; ++ni)                  \
          acc[AH][BG][mi][ni] = __builtin_amdgcn_mfma_i32_16x16x64_i8(    \
              af[mi][kk], BSRC[ni][kk], acc[AH][BG][mi][ni], 0, 0, 0);    \
    __builtin_amdgcn_s_setprio(0);                                        \
  } while (0)

// C[m][o] = xs[m] * scale[o] * (int dot of Xq[m,:], Wq[o,:]) + bias[o]
// Xq:[M][K] i8, Wq:[N][K] i8 (B^T layout), C:[M][N] f32.
// Round-6 proven schedule: 256x256 tile, 4 quadrant-phases/K-tile (Gray
// order A0B0,A0B1,A1B1,A1B0), B0/B1 register-resident, 2 barriers/K-tile,
// counted vmcnt(4) immediately before the tile barrier (never 0 mid-loop).
__global__ __launch_bounds__(512, 2) void gemm_kernel(
    const signed char* __restrict__ A,
    const signed char* __restrict__ B,
    const float* __restrict__ scale,
    const float* __restrict__ xs,
    const float* __restrict__ bias,
    float* __restrict__ C)
{
    extern __shared__ signed char lds[];   // 2 x 64KB

    // bijective XCD swizzle: nwg = 16*64 = 1024, divisible by 8
    const int nwg = (M_DIM / BM) * (N_DIM / BN);
    const int cpx = nwg / 8;
    int bid = blockIdx.x;
    int swz = (bid & 7) * cpx + (bid >> 3);
    const int ntn = N_DIM / BN;               // 64
    int tm = swz / ntn;
    int tn = swz % ntn;

    int tid  = threadIdx.x;
    int lane = tid & 63;
    int wid  = tid >> 6;      // 8 waves: 2 (M) x 4 (N)
    int wm   = wid >> 2;      // 0..1
    int wn   = wid & 3;       // 0..3
    int l15  = lane & 15;
    int lg   = lane >> 4;

    const signed char* Ab = A + (size_t)tm * BM * K_DIM;
    const signed char* Bb = B + (size_t)tn * BN * K_DIM;

    // Stage one half-tile (128 rows x 128 B = 16KB) into buffer `buf`, slot
    // `half` (0=A0,1=A1,2=B0,3=B1), K-tile t.  2 gload_lds per thread.
    // Chunk swizzle ch^(row&7) on the GLOBAL source (rule #21); LDS dest
    // linear.
    auto STAGE = [&](int buf, int half, int t) {
        const signed char* gbase = (half < 2)
            ? Ab + (size_t)(half * 128) * K_DIM
            : Bb + (size_t)((half - 2) * 128) * K_DIM;
        signed char* dbase = lds + buf * BUF_B + half * HALF_B;
        #pragma unroll
        for (int i = 0; i < 2; ++i) {
            int flat = i * 512 + tid;            // 16B-chunk id 0..1023
            int row = flat >> 3, ch = flat & 7;
            const signed char* src =
                gbase + (size_t)row * K_DIM + t * BKB + ((ch ^ (row & 7)) * 16);
            __builtin_amdgcn_global_load_lds(
                (const __attribute__((address_space(1))) unsigned int*)src,
                (__attribute__((address_space(3))) unsigned int*)(dbase + flat * 16),
                16, 0, 0);
        }
    };

    i32x4 acc[2][2][4][2];
    #pragma unroll
    for (int a0 = 0; a0 < 2; ++a0)
      #pragma unroll
      for (int g0 = 0; g0 < 2; ++g0)
        #pragma unroll
        for (int mi = 0; mi < 4; ++mi)
          #pragma unroll
          for (int ni = 0; ni < 2; ++ni)
            acc[a0][g0][mi][ni] = (i32x4){0, 0, 0, 0};

    i32x4 af[4][2], b0[2][2], b1[2][2];

    // Prologue: tile0 complete + A0(1),B1(1) in flight (steady state).
    STAGE(0, 0, 0);   // A0(0)
    STAGE(0, 2, 0);   // B0(0)
    STAGE(0, 3, 0);   // B1(0)
    STAGE(0, 1, 0);   // A1(0)
    STAGE(1, 0, 1);   // A0(1)
    STAGE(1, 3, 1);   // B1(1)
    asm volatile("s_waitcnt vmcnt(4)" ::: "memory");  // tile0's 8 loads landed

    for (int t = 0; t < NT; ++t) {
        const signed char* lb = lds + (t & 1) * BUF_B;
        const bool s1 = (t + 1) < NT;
        const bool s2 = (t + 2) < NT;

        BARRIER();                              // tile-boundary barrier
        if (s1) STAGE((t + 1) & 1, 1, t + 1);   // A1(t+1): slot retired P3(t-1)
        READ_A(0);
        READ_B(b0, 0);
        MFMA16(b0, 0, 0);                       // P1: A0 x B0
        if (s1) STAGE((t + 1) & 1, 2, t + 1);   // B0(t+1): slot retired P1(t-1)
        READ_B(b1, 1);
        MFMA16(b1, 0, 1);                       // P2: A0 x B1
        BARRIER();                              // mid-tile barrier
        if (s2) STAGE(t & 1, 0, t + 2);         // A0(t+2): A0(t) reads done P1
        READ_A(1);
        MFMA16(b1, 1, 1);                       // P3: A1 x B1
        if (s2) STAGE(t & 1, 3, t + 2);         // B1(t+2): B1(t) reads done P2
        MFMA16(b0, 1, 0);                       // P4: A1 x B0 (no reads)
        // Boundary wait BEFORE next tile's barrier.  Leaves 2 stages in flight.
        if (s2) asm volatile("s_waitcnt vmcnt(4)" ::: "memory");
        else    asm volatile("s_waitcnt vmcnt(0)" ::: "memory");
    }

    // Epilogue: 16x16 C/D layout col = lane&15, row = (lane>>4)*4 + reg (m89;
    // dtype-independent incl. i8 per m121-128).
    #pragma unroll
    for (int AH = 0; AH < 2; ++AH)
      #pragma unroll
      for (int BG = 0; BG < 2; ++BG)
        #pragma unroll
        for (int ni = 0; ni < 2; ++ni) {
            int col = tn * BN + BG * 128 + wn * 32 + ni * 16 + l15;
            float s = scale[col];
            float b = bias[col];
            #pragma unroll
            for (int mi = 0; mi < 4; ++mi) {
                int row0 = tm * BM + AH * 128 + wm * 64 + mi * 16 + lg * 4;
                float4 x4 = *reinterpret_cast<const float4*>(xs + row0);
                float xv[4] = {x4.x, x4.y, x4.z, x4.w};
                #pragma unroll
                for (int r = 0; r < 4; ++r)
                    C[(size_t)(row0 + r) * N_DIM + col] =
                        (float)acc[AH][BG][mi][ni][r] * (s * xv[r]) + b;
            }
        }
}

// safety net if workspace is too small
__global__ void naive_kernel(const float* __restrict__ x,
                             const int* __restrict__ w,
                             const float* __restrict__ scale,
                             const float* __restrict__ bias,
                             float* __restrict__ out) {
    long long idx = (long long)blockIdx.x * blockDim.x + threadIdx.x;
    long long total = (long long)M_DIM * N_DIM;
    if (idx >= total) return;
    int m = (int)(idx / N_DIM);
    int o = (int)(idx % N_DIM);
    const float* xr = x + (size_t)m * K_DIM;
    const int* wr = w + (size_t)o * K_DIM;
    float sum = 0.f;
    for (int k = 0; k < K_DIM; ++k) sum += xr[k] * (float)wr[k];
    out[idx] = sum * scale[o] + bias[o];
}

extern "C" void kernel_launch(void* const* d_in, const int* in_sizes, int n_in,
                              void* d_out, int out_size, void* d_ws, size_t ws_size,
                              hipStream_t stream)
{
    const float* x     = (const float*)d_in[0];
    const int*   w     = (const int*)d_in[1];
    const float* scale = (const float*)d_in[2];
    const float* bias  = (const float*)d_in[3];
    float*       out   = (float*)d_out;

    const size_t needW = (size_t)N_DIM * K_DIM;            // 64MB int8
    const size_t needX = (size_t)M_DIM * K_DIM;            // 16MB int8
    const size_t needS = (size_t)M_DIM * sizeof(float);    // 16KB

    if (ws_size >= needW + needX + needS) {
        signed char* Wq = (signed char*)d_ws;
        signed char* Xq = (signed char*)((char*)d_ws + needW);
        float*       xs = (float*)((char*)d_ws + needW + needX);
        hipLaunchKernelGGL(cvt_w_kernel, dim3(2048), dim3(256), 0, stream,
                           w, Wq, N_DIM * K_DIM);
        hipLaunchKernelGGL(quant_x_kernel, dim3(M_DIM), dim3(256), 0, stream,
                           x, Xq, xs);
        hipLaunchKernelGGL(gemm_kernel, dim3((M_DIM / BM) * (N_DIM / BN)), dim3(512),
                           LDS_BYTES, stream, Xq, Wq, scale, xs, bias, out);
    } else {
        long long total = (long long)M_DIM * N_DIM;
        int blocks = (int)((total + 255) / 256);
        hipLaunchKernelGGL(naive_kernel, dim3(blocks), dim3(256), 0, stream,
                           x, w, scale, bias, out);
    }
}